// Round 7
// baseline (562.745 us; speedup 1.0000x reference)
//
#include <hip/hip_runtime.h>
#include <hip/hip_bf16.h>

// GCN forward: 3 layers, N=100000, HIDDEN=128, E=600000.
// Aggregation is linear => aggregate first (A_norm * x), then GEMM by W.
// CSR (pull) built per launch via counting sort; no per-layer atomics.
// Round-19: k_agg is at its pattern ceiling (3 attempts flat at 62us, 45% of
// streaming peak = fabric limit for random 512B gathers; L3 absorbs re-reads).
// nt y-stores were neutral (FETCH -1%) -> L2 eviction theory dead. Dispatch-
// count reduction was neutral -> gaps are small. Remaining lever: GEMM block
// overheads. This round makes the GEMM PERSISTENT:
//   - 512 blocks (2/CU by 68KB LDS) grid-stride over 782 tiles;
//   - W planes staged ONCE per block (W re-read 100->65 MB, 782->512 barriers);
//   - per tile: nt A-frag loads -> MFMA -> epilogue, NO barrier (W_lds is RO);
//   - MFMA/FMA order per output element identical -> absmax unchanged.
// Dead ends (do not reintroduce): grid-barrier fusion (40us/phase), agg+gemm
// LDS fusion (1 blk/CU kills gather occupancy), deeper agg pipelines (flat),
// nt-stores-as-L2-fix (neutral; kept only as harmless).

#define HID 128

typedef __attribute__((ext_vector_type(8))) short short8;     // 8 bf16 (A/B frag)
typedef __attribute__((ext_vector_type(4))) float floatx4;    // C/D frag

#define WLDS 136   // padded row stride (ushorts): 272 B -> balanced LDS banks

// ---------- preprocessing ----------
// cnt is memset to 0 on stream; cnt[i] = deg_in(i); scans add +1 (self-loop).

// fused: blocks [0, packBlocks) pack W; blocks [packBlocks, ...) count edges
// (int4 over the dst row; counting is order-free so vectorization is safe).
__global__ void k_count_pack(const int* __restrict__ ei, int* cnt, int E,
                             const float* __restrict__ Ws, ushort* Whp,
                             ushort* Wlp, int nlayers, int packBlocks) {
    if ((int)blockIdx.x < packBlocks) {
        int idx = blockIdx.x * blockDim.x + threadIdx.x;  // l*16384 + n*128 + k
        if (idx < nlayers * HID * HID) {
            int l = idx >> 14;
            int nn = (idx >> 7) & 127;
            int k = idx & 127;
            float w = Ws[(size_t)l * HID * HID + k * HID + nn];
            __hip_bfloat16 hi = __float2bfloat16(w);
            float lo = w - __bfloat162float(hi);
            __hip_bfloat16 lo16 = __float2bfloat16(lo);
            Whp[idx] = *(ushort*)&hi;
            Wlp[idx] = *(ushort*)&lo16;
        }
        return;
    }
    int b = blockIdx.x - packBlocks;
    int quads = E >> 2;
    int qid = b * blockDim.x + threadIdx.x;
    if (qid < quads) {
        int4 d = ((const int4*)(ei + E))[qid];
        atomicAdd(&cnt[d.x], 1);
        atomicAdd(&cnt[d.y], 1);
        atomicAdd(&cnt[d.z], 1);
        atomicAdd(&cnt[d.w], 1);
    }
    if (b == 0) {
        int rem = E & 3;
        if ((int)threadIdx.x < rem)
            atomicAdd(&cnt[ei[E + (quads << 2) + threadIdx.x]], 1);
    }
}

// chunk sums: CHUNK=1024 (256 thr x 4); +1 per element = self-loop
__global__ void k_scanA(const int* __restrict__ cnt, int* csum, int n) {
    __shared__ int sd[256];
    int t = threadIdx.x;
    int base = blockIdx.x * 1024 + t * 4;
    int s = 0;
#pragma unroll
    for (int j = 0; j < 4; j++) { int i = base + j; if (i < n) s += cnt[i] + 1; }
    sd[t] = s; __syncthreads();
    for (int off = 128; off > 0; off >>= 1) {
        if (t < off) sd[t] += sd[t + off];
        __syncthreads();
    }
    if (t == 0) csum[blockIdx.x] = sd[0];
}

// scanC with scanB inlined (each block redundantly scans the <=256 chunk sums)
// + node init: offsets, dinv, cursor, self-loop adj entry.
__global__ void k_scanC(const int* __restrict__ cnt, const int* __restrict__ csum,
                        int* offsets, int* cursor, float* dinv,
                        int2* adj, int n, int nchunk) {
    __shared__ int sd[256];
    __shared__ int cb_sh, tot_sh;
    int t = threadIdx.x;

    // inline exclusive-scan of chunk sums
    int v = (t < nchunk) ? csum[t] : 0;
    sd[t] = v; __syncthreads();
    for (int off = 1; off < 256; off <<= 1) {
        int u = (t >= off) ? sd[t - off] : 0;
        __syncthreads();
        sd[t] += u;
        __syncthreads();
    }
    if (t == (int)blockIdx.x) cb_sh = sd[t] - v;   // exclusive chunk base
    if (t == nchunk - 1) tot_sh = sd[t];           // grand total = E + N
    __syncthreads();
    int chunkbase = cb_sh;
    if (blockIdx.x == 0 && t == 0) offsets[n] = tot_sh;

    int base = blockIdx.x * 1024 + t * 4;
    int c[4]; int s = 0;
#pragma unroll
    for (int j = 0; j < 4; j++) {
        c[j] = (base + j < n) ? cnt[base + j] + 1 : 0;   // +1 self-loop
        s += c[j];
    }
    sd[t] = s; __syncthreads();
    for (int off = 1; off < 256; off <<= 1) {
        int vv = (t >= off) ? sd[t - off] : 0;
        __syncthreads();
        sd[t] += vv;
        __syncthreads();
    }
    int run = sd[t] - s + chunkbase;
#pragma unroll
    for (int j = 0; j < 4; j++) {
        int i = base + j;
        if (i < n) {
            offsets[i] = run;
            float di = rsqrtf((float)c[j]);   // deg >= 1 (self-loop)
            dinv[i] = di;
            cursor[i] = run + 1;
            adj[run] = make_int2(i, __float_as_int(di * di));  // self-loop first
        }
        run += c[j];
    }
}

// kept identical mapping: atomic edge-ordering (FP sum order) unchanged
__global__ void k_fill_edges(const int* __restrict__ ei, int* cursor,
                             const float* __restrict__ dinv,
                             int2* adj, int E) {
    int e = blockIdx.x * blockDim.x + threadIdx.x;
    if (e >= E) return;
    int s = ei[e];
    int d = ei[E + e];
    int pos = atomicAdd(&cursor[d], 1);
    adj[pos] = make_int2(s, __float_as_int(dinv[s] * dinv[d]));
}

// ---------- per-layer: pull aggregation (round-14 body, verified) ----------
// One wave per node (grid-stride). Wave quarters: q>>1 = edge-slot parity,
// q&1 = feature half. Depth-3 pipeline; clamped always-valid loads; per-lane
// FMA order fixed -> bit-identical output. At the random-gather fabric ceiling.

__global__ __launch_bounds__(256) void k_agg(const float* __restrict__ x,
                                             const int* __restrict__ offsets,
                                             const int2* __restrict__ adj,
                                             ushort* __restrict__ yh,
                                             ushort* __restrict__ yl, int n) {
    int gid = blockIdx.x * blockDim.x + threadIdx.x;
    int lane = gid & 63;
    int q    = lane >> 4;            // quarter 0..3
    int ql   = lane & 15;
    int f4   = (q & 1) * 16 + ql;    // float4 index within row, [0,32)
    int epar = q >> 1;               // edge-slot parity 0/1
    int nwaves = (gridDim.x * blockDim.x) >> 6;

    int node0 = gid >> 6;
    int nbeg = 0, nend = 0;
    if (node0 < n) { nbeg = offsets[node0]; nend = offsets[node0 + 1]; }

    for (int node = node0; node < n; node += nwaves) {
        int beg = nbeg;
        int end = nend;
        int nxt = node + nwaves;
        if (nxt < n) { nbeg = offsets[nxt]; nend = offsets[nxt + 1]; }

        float4 acc = {0.f, 0.f, 0.f, 0.f};

        int e0 = beg + epar;
        int c0 = e0 < end ? e0 : end - 1;
        int2 a0 = adj[c0];
        int e1 = e0 + 2;
        int c1 = e1 < end ? e1 : end - 1;
        int2 a1 = adj[c1];
        int e2 = e0 + 4;
        int c2 = e2 < end ? e2 : end - 1;
        int2 a2 = adj[c2];
        float w0 = e0 < end ? __int_as_float(a0.y) : 0.f;
        float w1 = e1 < end ? __int_as_float(a1.y) : 0.f;
        float w2 = e2 < end ? __int_as_float(a2.y) : 0.f;
        float4 v0 = ((const float4*)(x + (size_t)a0.x * HID))[f4];
        float4 v1 = ((const float4*)(x + (size_t)a1.x * HID))[f4];
        int s2 = a2.x;

        for (int e = beg + 4; e < end; e += 2) {
            int e3 = e + 2 + epar;
            int c3 = e3 < end ? e3 : end - 1;
            int2 a3 = adj[c3];
            float w3 = e3 < end ? __int_as_float(a3.y) : 0.f;

            float4 v2 = ((const float4*)(x + (size_t)s2 * HID))[f4];

            acc.x += w0 * v0.x;
            acc.y += w0 * v0.y;
            acc.z += w0 * v0.z;
            acc.w += w0 * v0.w;

            v0 = v1; v1 = v2;
            w0 = w1; w1 = w2; w2 = w3;
            s2 = a3.x;
        }
        acc.x += w0 * v0.x;
        acc.y += w0 * v0.y;
        acc.z += w0 * v0.z;
        acc.w += w0 * v0.w;
        acc.x += w1 * v1.x;
        acc.y += w1 * v1.y;
        acc.z += w1 * v1.z;
        acc.w += w1 * v1.w;

        acc.x += __shfl_xor(acc.x, 32);
        acc.y += __shfl_xor(acc.y, 32);
        acc.z += __shfl_xor(acc.z, 32);
        acc.w += __shfl_xor(acc.w, 32);
        if (lane < 32) {
            float a[4] = {acc.x, acc.y, acc.z, acc.w};
            ushort hp[4], lp[4];
#pragma unroll
            for (int j = 0; j < 4; j++) {
                __hip_bfloat16 hi = __float2bfloat16(a[j]);
                float lo = a[j] - __bfloat162float(hi);
                __hip_bfloat16 lo16 = __float2bfloat16(lo);
                hp[j] = *(ushort*)&hi;
                lp[j] = *(ushort*)&lo16;
            }
            unsigned long long hv, lv;
            __builtin_memcpy(&hv, hp, 8);
            __builtin_memcpy(&lv, lp, 8);
            __builtin_nontemporal_store(hv, ((unsigned long long*)(yh + (size_t)node * HID)) + lane);
            __builtin_nontemporal_store(lv, ((unsigned long long*)(yl + (size_t)node * HID)) + lane);
        }
    }
}

// ---------- per-layer: persistent GEMM (split-bf16 MFMA 16x16x32) ----------
// 512 blocks (2/CU by 68KB LDS) grid-stride over ntiles 128-row tiles.
// W planes staged ONCE per block; after the single barrier W_lds is read-only
// and the tile loop has NO barriers: nt A-frag loads -> MFMA -> epilogue.
// MFMA order per (ks,c) identical to round-12. C/D: col=lane&15,
// row=(lane>>4)*4+reg.

__global__ __launch_bounds__(256, 2) void k_gemm_mfma(const ushort* __restrict__ yh,
                                                      const ushort* __restrict__ yl,
                                                      const ushort* __restrict__ Whp,
                                                      const ushort* __restrict__ Wlp,
                                                      const float* __restrict__ bias,
                                                      float* __restrict__ out, int n,
                                                      int ntiles) {
    __shared__ ushort Wh_lds[HID * WLDS];   // 34816 B
    __shared__ ushort Wl_lds[HID * WLDS];   // 34816 B
    int t = threadIdx.x;
    int wave = t >> 6;
    int lane = t & 63;
    int m16  = lane & 15;
    int oct  = lane >> 4;            // k-octet 0..3

    // stage W planes once: 128 rows x 16 uint4 per plane
    for (int idx = t; idx < HID * 16; idx += 256) {
        int r = idx >> 4, c8 = idx & 15;
        ((uint4*)(Wh_lds + r * WLDS))[c8] = ((const uint4*)(Whp + r * HID))[c8];
        ((uint4*)(Wl_lds + r * WLDS))[c8] = ((const uint4*)(Wlp + r * HID))[c8];
    }
    __syncthreads();

    for (int tile = blockIdx.x; tile < ntiles; tile += gridDim.x) {
        // A fragments for this tile (nt: y is read exactly once, keep L2 for W/out)
        short8 ah[2][4], al[2][4];
#pragma unroll
        for (int mt = 0; mt < 2; mt++) {
            int rowA = tile * 128 + wave * 32 + mt * 16 + m16;
            const ushort* hb = yh + (size_t)rowA * HID + oct * 8;
            const ushort* lb = yl + (size_t)rowA * HID + oct * 8;
#pragma unroll
            for (int ks = 0; ks < 4; ks++) {
                ah[mt][ks] = __builtin_nontemporal_load((const short8*)(hb + ks * 32));
                al[mt][ks] = __builtin_nontemporal_load((const short8*)(lb + ks * 32));
            }
        }

        floatx4 acc0[8], acc1[8];
#pragma unroll
        for (int c = 0; c < 8; c++) {
            acc0[c] = (floatx4){0.f, 0.f, 0.f, 0.f};
            acc1[c] = (floatx4){0.f, 0.f, 0.f, 0.f};
        }

#pragma unroll
        for (int ks = 0; ks < 4; ks++) {                    // K = 128 = 4 x 32
#pragma unroll
            for (int c = 0; c < 8; c++) {                   // 8 col-tiles of 16
                const ushort* bp = Wh_lds + (c * 16 + m16) * WLDS + ks * 32 + oct * 8;
                const ushort* bq = Wl_lds + (c * 16 + m16) * WLDS + ks * 32 + oct * 8;
                short8 bh = *(const short8*)bp;
                short8 bl = *(const short8*)bq;
                acc0[c] = __builtin_amdgcn_mfma_f32_16x16x32_bf16(ah[0][ks], bh, acc0[c], 0, 0, 0);
                acc0[c] = __builtin_amdgcn_mfma_f32_16x16x32_bf16(ah[0][ks], bl, acc0[c], 0, 0, 0);
                acc0[c] = __builtin_amdgcn_mfma_f32_16x16x32_bf16(al[0][ks], bh, acc0[c], 0, 0, 0);
                acc1[c] = __builtin_amdgcn_mfma_f32_16x16x32_bf16(ah[1][ks], bh, acc1[c], 0, 0, 0);
                acc1[c] = __builtin_amdgcn_mfma_f32_16x16x32_bf16(ah[1][ks], bl, acc1[c], 0, 0, 0);
                acc1[c] = __builtin_amdgcn_mfma_f32_16x16x32_bf16(al[1][ks], bh, acc1[c], 0, 0, 0);
            }
        }

        // epilogue: bias + relu + store (C/D: col=lane&15, row=(lane>>4)*4+reg)
#pragma unroll
        for (int mt = 0; mt < 2; mt++) {
            int rowbase = tile * 128 + wave * 32 + mt * 16 + oct * 4;
#pragma unroll
            for (int c = 0; c < 8; c++) {
                int col = c * 16 + m16;
                float b = bias[col];
                floatx4 a = mt == 0 ? acc0[c] : acc1[c];
#pragma unroll
                for (int r = 0; r < 4; r++) {
                    int row = rowbase + r;
                    if (row < n) {
                        float v = fmaxf(a[r] + b, 0.f);
                        out[(size_t)row * HID + col] = v;
                    }
                }
            }
        }
    }
}

// ---------- launch ----------

extern "C" void kernel_launch(void* const* d_in, const int* in_sizes, int n_in,
                              void* d_out, int out_size, void* d_ws, size_t ws_size,
                              hipStream_t stream) {
    const int* ei = (const int*)d_in[0];          // (2, E) int32
    const float* emb = (const float*)d_in[1];     // (N, 128)
    const float* Ws = (const float*)d_in[2];      // (3, 128, 128)
    const float* bs = (const float*)d_in[3];      // (3, 128)

    const int E = in_sizes[0] / 2;                // 600000
    const int N = in_sizes[1] / HID;              // 100000
    const int NL = in_sizes[3] / HID;             // 3
    const int TOT = E + N;
    const int NPAD = ((N + 127) / 128) * 128;     // 100096 (A-loads unmasked)

    // workspace carve-up (256B aligned)
    char* p = (char*)d_ws;
    auto carve = [&](size_t bytes) {
        char* r = p;
        p += (bytes + 255) & ~(size_t)255;
        return (void*)r;
    };
    int*    cnt      = (int*)   carve((size_t)N * 4);
    int*    offsets  = (int*)   carve((size_t)(N + 1) * 4);
    int*    cursor   = (int*)   carve((size_t)N * 4);
    float*  dinv     = (float*) carve((size_t)N * 4);
    int*    csum     = (int*)   carve(1024 * 4);
    int2*   adj      = (int2*)  carve((size_t)TOT * 8);
    ushort* yh       = (ushort*)carve((size_t)NPAD * HID * 2);
    ushort* yl       = (ushort*)carve((size_t)NPAD * HID * 2);
    ushort* Whp      = (ushort*)carve((size_t)NL * HID * HID * 2);
    ushort* Wlp      = (ushort*)carve((size_t)NL * HID * HID * 2);
    float*  xbufA    = (float*) carve((size_t)N * HID * 4);
    float*  xbufB    = (float*) d_out;    // l0 and l2 outputs land here

    const int NCHUNK = (N + 1023) / 1024;   // 98 <= 256 (scan capacity)
    const int packBlocks = (NL * HID * HID + 255) / 256;        // 192
    const int edgeBlocks = ((E >> 2) + 255) / 256;              // 586
    const int cpBlocks = packBlocks + (edgeBlocks > 0 ? edgeBlocks : 1);

    (void)hipMemsetAsync(cnt, 0, (size_t)N * 4, stream);
    k_count_pack<<<cpBlocks, 256, 0, stream>>>(ei, cnt, E, Ws, Whp, Wlp, NL,
                                               packBlocks);
    k_scanA<<<NCHUNK, 256, 0, stream>>>(cnt, csum, N);
    k_scanC<<<NCHUNK, 256, 0, stream>>>(cnt, csum, offsets, cursor, dinv,
                                        adj, N, NCHUNK);
    k_fill_edges<<<(E + 255) / 256, 256, 0, stream>>>(ei, cursor, dinv, adj, E);

    // grid-stride agg: 2048 blocks (8 per CU, 32 waves/CU), ~12 nodes per wave
    const int aggBlocks = 2048;
    const int ntiles = NPAD / 128;        // 782
    const int gemmBlocks = 512;           // persistent, 2 blocks/CU
    // l0: emb -> d_out, l1: d_out -> xbufA, l2: xbufA -> d_out
    const float* x = emb;
    for (int l = 0; l < NL; l++) {
        float* o = (l == 1) ? xbufA : xbufB;
        k_agg<<<aggBlocks, 256, 0, stream>>>(x, offsets, adj, yh, yl, N);
        k_gemm_mfma<<<gemmBlocks, 256, 0, stream>>>(yh, yl,
                                                    Whp + (size_t)l * HID * HID,
                                                    Wlp + (size_t)l * HID * HID,
                                                    bs + (size_t)l * HID, o, N,
                                                    ntiles);
        x = o;
    }
}

// Round 9
// 429.652 us; speedup vs baseline: 1.3098x; 1.3098x over previous
//
#include <hip/hip_runtime.h>
#include <hip/hip_bf16.h>

// GCN forward: 3 layers, N=100000, HIDDEN=128, E=600000.
// Aggregation is linear => aggregate first (A_norm * x), then GEMM by W.
// CSR (pull) built per launch via counting sort; no per-layer atomics.
// Round-21 = round-20 resubmitted verbatim (bench infra failed twice with no
// compile/test verdict; kernel is race-free: LDS re-alias happens strictly
// after a __syncthreads covering all W reads). Structure:
//   - split GEMM, 782 blocks (round-12 MFMA shape) + LDS-staged epilogue:
//     after MFMA, reuse the contiguous 68KB W LDS as a 128x129-float padded
//     tile, write bias+relu there, stream out as float2/lane = full 128B
//     lines, killing the ~51MB out read-for-ownership seen in round-19's
//     counters (FETCH 108MB = y 51 + out-RFO 51 + W~1).
//   - k_agg round-14 body (verified, at its random-gather fabric ceiling).
// Math order identical everywhere; floats round-trip LDS exactly -> absmax
// unchanged (0.00390625).
// Dead ends (do not reintroduce): grid-barrier fusion (40us/phase), agg+gemm
// LDS fusion (1 blk/CU kills gather occupancy), deeper agg pipelines (flat at
// 62us x3 = pattern ceiling), persistent GEMM (spills+serialization 80us),
// nt-stores-as-L2-fix (neutral, kept as harmless).

#define HID 128

typedef __attribute__((ext_vector_type(8))) short short8;     // 8 bf16 (A/B frag)
typedef __attribute__((ext_vector_type(4))) float floatx4;    // C/D frag

#define WLDS 136   // padded row stride (ushorts): 272 B -> balanced LDS banks
#define YSTR 129   // padded row stride (floats) for the epilogue tile

// ---------- preprocessing ----------
// cnt is memset to 0 on stream; cnt[i] = deg_in(i); scans add +1 (self-loop).

// fused: blocks [0, packBlocks) pack W; blocks [packBlocks, ...) count edges
// (int4 over the dst row; counting is order-free so vectorization is safe).
__global__ void k_count_pack(const int* __restrict__ ei, int* cnt, int E,
                             const float* __restrict__ Ws, ushort* Whp,
                             ushort* Wlp, int nlayers, int packBlocks) {
    if ((int)blockIdx.x < packBlocks) {
        int idx = blockIdx.x * blockDim.x + threadIdx.x;  // l*16384 + n*128 + k
        if (idx < nlayers * HID * HID) {
            int l = idx >> 14;
            int nn = (idx >> 7) & 127;
            int k = idx & 127;
            float w = Ws[(size_t)l * HID * HID + k * HID + nn];
            __hip_bfloat16 hi = __float2bfloat16(w);
            float lo = w - __bfloat162float(hi);
            __hip_bfloat16 lo16 = __float2bfloat16(lo);
            Whp[idx] = *(ushort*)&hi;
            Wlp[idx] = *(ushort*)&lo16;
        }
        return;
    }
    int b = blockIdx.x - packBlocks;
    int quads = E >> 2;
    int qid = b * blockDim.x + threadIdx.x;
    if (qid < quads) {
        int4 d = ((const int4*)(ei + E))[qid];
        atomicAdd(&cnt[d.x], 1);
        atomicAdd(&cnt[d.y], 1);
        atomicAdd(&cnt[d.z], 1);
        atomicAdd(&cnt[d.w], 1);
    }
    if (b == 0) {
        int rem = E & 3;
        if ((int)threadIdx.x < rem)
            atomicAdd(&cnt[ei[E + (quads << 2) + threadIdx.x]], 1);
    }
}

// chunk sums: CHUNK=1024 (256 thr x 4); +1 per element = self-loop
__global__ void k_scanA(const int* __restrict__ cnt, int* csum, int n) {
    __shared__ int sd[256];
    int t = threadIdx.x;
    int base = blockIdx.x * 1024 + t * 4;
    int s = 0;
#pragma unroll
    for (int j = 0; j < 4; j++) { int i = base + j; if (i < n) s += cnt[i] + 1; }
    sd[t] = s; __syncthreads();
    for (int off = 128; off > 0; off >>= 1) {
        if (t < off) sd[t] += sd[t + off];
        __syncthreads();
    }
    if (t == 0) csum[blockIdx.x] = sd[0];
}

// scanC with scanB inlined (each block redundantly scans the <=256 chunk sums)
// + node init: offsets, dinv, cursor, self-loop adj entry.
__global__ void k_scanC(const int* __restrict__ cnt, const int* __restrict__ csum,
                        int* offsets, int* cursor, float* dinv,
                        int2* adj, int n, int nchunk) {
    __shared__ int sd[256];
    __shared__ int cb_sh, tot_sh;
    int t = threadIdx.x;

    // inline exclusive-scan of chunk sums
    int v = (t < nchunk) ? csum[t] : 0;
    sd[t] = v; __syncthreads();
    for (int off = 1; off < 256; off <<= 1) {
        int u = (t >= off) ? sd[t - off] : 0;
        __syncthreads();
        sd[t] += u;
        __syncthreads();
    }
    if (t == (int)blockIdx.x) cb_sh = sd[t] - v;   // exclusive chunk base
    if (t == nchunk - 1) tot_sh = sd[t];           // grand total = E + N
    __syncthreads();
    int chunkbase = cb_sh;
    if (blockIdx.x == 0 && t == 0) offsets[n] = tot_sh;

    int base = blockIdx.x * 1024 + t * 4;
    int c[4]; int s = 0;
#pragma unroll
    for (int j = 0; j < 4; j++) {
        c[j] = (base + j < n) ? cnt[base + j] + 1 : 0;   // +1 self-loop
        s += c[j];
    }
    sd[t] = s; __syncthreads();
    for (int off = 1; off < 256; off <<= 1) {
        int vv = (t >= off) ? sd[t - off] : 0;
        __syncthreads();
        sd[t] += vv;
        __syncthreads();
    }
    int run = sd[t] - s + chunkbase;
#pragma unroll
    for (int j = 0; j < 4; j++) {
        int i = base + j;
        if (i < n) {
            offsets[i] = run;
            float di = rsqrtf((float)c[j]);   // deg >= 1 (self-loop)
            dinv[i] = di;
            cursor[i] = run + 1;
            adj[run] = make_int2(i, __float_as_int(di * di));  // self-loop first
        }
        run += c[j];
    }
}

// kept identical mapping: atomic edge-ordering (FP sum order) unchanged
__global__ void k_fill_edges(const int* __restrict__ ei, int* cursor,
                             const float* __restrict__ dinv,
                             int2* adj, int E) {
    int e = blockIdx.x * blockDim.x + threadIdx.x;
    if (e >= E) return;
    int s = ei[e];
    int d = ei[E + e];
    int pos = atomicAdd(&cursor[d], 1);
    adj[pos] = make_int2(s, __float_as_int(dinv[s] * dinv[d]));
}

// ---------- per-layer: pull aggregation (round-14 body, verified) ----------
// One wave per node (grid-stride). Wave quarters: q>>1 = edge-slot parity,
// q&1 = feature half. Depth-3 pipeline; clamped always-valid loads; per-lane
// FMA order fixed -> bit-identical output. At the random-gather fabric ceiling.

__global__ __launch_bounds__(256) void k_agg(const float* __restrict__ x,
                                             const int* __restrict__ offsets,
                                             const int2* __restrict__ adj,
                                             ushort* __restrict__ yh,
                                             ushort* __restrict__ yl, int n) {
    int gid = blockIdx.x * blockDim.x + threadIdx.x;
    int lane = gid & 63;
    int q    = lane >> 4;            // quarter 0..3
    int ql   = lane & 15;
    int f4   = (q & 1) * 16 + ql;    // float4 index within row, [0,32)
    int epar = q >> 1;               // edge-slot parity 0/1
    int nwaves = (gridDim.x * blockDim.x) >> 6;

    int node0 = gid >> 6;
    int nbeg = 0, nend = 0;
    if (node0 < n) { nbeg = offsets[node0]; nend = offsets[node0 + 1]; }

    for (int node = node0; node < n; node += nwaves) {
        int beg = nbeg;
        int end = nend;
        int nxt = node + nwaves;
        if (nxt < n) { nbeg = offsets[nxt]; nend = offsets[nxt + 1]; }

        float4 acc = {0.f, 0.f, 0.f, 0.f};

        int e0 = beg + epar;
        int c0 = e0 < end ? e0 : end - 1;
        int2 a0 = adj[c0];
        int e1 = e0 + 2;
        int c1 = e1 < end ? e1 : end - 1;
        int2 a1 = adj[c1];
        int e2 = e0 + 4;
        int c2 = e2 < end ? e2 : end - 1;
        int2 a2 = adj[c2];
        float w0 = e0 < end ? __int_as_float(a0.y) : 0.f;
        float w1 = e1 < end ? __int_as_float(a1.y) : 0.f;
        float w2 = e2 < end ? __int_as_float(a2.y) : 0.f;
        float4 v0 = ((const float4*)(x + (size_t)a0.x * HID))[f4];
        float4 v1 = ((const float4*)(x + (size_t)a1.x * HID))[f4];
        int s2 = a2.x;

        for (int e = beg + 4; e < end; e += 2) {
            int e3 = e + 2 + epar;
            int c3 = e3 < end ? e3 : end - 1;
            int2 a3 = adj[c3];
            float w3 = e3 < end ? __int_as_float(a3.y) : 0.f;

            float4 v2 = ((const float4*)(x + (size_t)s2 * HID))[f4];

            acc.x += w0 * v0.x;
            acc.y += w0 * v0.y;
            acc.z += w0 * v0.z;
            acc.w += w0 * v0.w;

            v0 = v1; v1 = v2;
            w0 = w1; w1 = w2; w2 = w3;
            s2 = a3.x;
        }
        acc.x += w0 * v0.x;
        acc.y += w0 * v0.y;
        acc.z += w0 * v0.z;
        acc.w += w0 * v0.w;
        acc.x += w1 * v1.x;
        acc.y += w1 * v1.y;
        acc.z += w1 * v1.z;
        acc.w += w1 * v1.w;

        acc.x += __shfl_xor(acc.x, 32);
        acc.y += __shfl_xor(acc.y, 32);
        acc.z += __shfl_xor(acc.z, 32);
        acc.w += __shfl_xor(acc.w, 32);
        if (lane < 32) {
            float a[4] = {acc.x, acc.y, acc.z, acc.w};
            ushort hp[4], lp[4];
#pragma unroll
            for (int j = 0; j < 4; j++) {
                __hip_bfloat16 hi = __float2bfloat16(a[j]);
                float lo = a[j] - __bfloat162float(hi);
                __hip_bfloat16 lo16 = __float2bfloat16(lo);
                hp[j] = *(ushort*)&hi;
                lp[j] = *(ushort*)&lo16;
            }
            unsigned long long hv, lv;
            __builtin_memcpy(&hv, hp, 8);
            __builtin_memcpy(&lv, lp, 8);
            __builtin_nontemporal_store(hv, ((unsigned long long*)(yh + (size_t)node * HID)) + lane);
            __builtin_nontemporal_store(lv, ((unsigned long long*)(yl + (size_t)node * HID)) + lane);
        }
    }
}

// ---------- per-layer: GEMM (round-12 shape + LDS-staged epilogue) ----------
// Block 256 thr = 4 waves; tile 128x128; W planes in LDS (one contiguous 68KB
// array -> 2 blocks/CU). A frags up-front, in flight behind the W staging.
// Inner loop: 2 ds_read_b128 + 6 MFMA. C/D: col=lane&15, row=(lane>>4)*4+reg.
// Epilogue v2: barrier, re-alias the W LDS as a 128x129-float padded tile,
// write bias+relu results there, barrier, stream to out as float2/lane =
// fully-covered 128B lines (kills the ~51MB read-for-ownership that the old
// 64B partial-line stores caused).

__global__ __launch_bounds__(256, 2) void k_gemm_mfma(const ushort* __restrict__ yh,
                                                      const ushort* __restrict__ yl,
                                                      const ushort* __restrict__ Whp,
                                                      const ushort* __restrict__ Wlp,
                                                      const float* __restrict__ bias,
                                                      float* __restrict__ out, int n) {
    __shared__ ushort Wlds[2 * HID * WLDS];   // 69632 B (contiguous; re-aliased)
    ushort* Wh_lds = Wlds;
    ushort* Wl_lds = Wlds + HID * WLDS;
    int t = threadIdx.x;
    int wave = t >> 6;
    int lane = t & 63;
    int m16  = lane & 15;
    int oct  = lane >> 4;            // k-octet 0..3

    short8 ah[2][4], al[2][4];
#pragma unroll
    for (int mt = 0; mt < 2; mt++) {
        int rowA = blockIdx.x * 128 + wave * 32 + mt * 16 + m16;
        const ushort* hb = yh + (size_t)rowA * HID + oct * 8;
        const ushort* lb = yl + (size_t)rowA * HID + oct * 8;
#pragma unroll
        for (int ks = 0; ks < 4; ks++) {
            ah[mt][ks] = *(const short8*)(hb + ks * 32);
            al[mt][ks] = *(const short8*)(lb + ks * 32);
        }
    }

    for (int idx = t; idx < HID * 16; idx += 256) {
        int r = idx >> 4, c8 = idx & 15;
        ((uint4*)(Wh_lds + r * WLDS))[c8] = ((const uint4*)(Whp + r * HID))[c8];
        ((uint4*)(Wl_lds + r * WLDS))[c8] = ((const uint4*)(Wlp + r * HID))[c8];
    }
    __syncthreads();

    floatx4 acc0[8], acc1[8];
#pragma unroll
    for (int c = 0; c < 8; c++) {
        acc0[c] = (floatx4){0.f, 0.f, 0.f, 0.f};
        acc1[c] = (floatx4){0.f, 0.f, 0.f, 0.f};
    }

#pragma unroll
    for (int ks = 0; ks < 4; ks++) {                    // K = 128 = 4 x 32
#pragma unroll
        for (int c = 0; c < 8; c++) {                   // 8 col-tiles of 16
            const ushort* bp = Wh_lds + (c * 16 + m16) * WLDS + ks * 32 + oct * 8;
            const ushort* bq = Wl_lds + (c * 16 + m16) * WLDS + ks * 32 + oct * 8;
            short8 bh = *(const short8*)bp;
            short8 bl = *(const short8*)bq;
            acc0[c] = __builtin_amdgcn_mfma_f32_16x16x32_bf16(ah[0][ks], bh, acc0[c], 0, 0, 0);
            acc0[c] = __builtin_amdgcn_mfma_f32_16x16x32_bf16(ah[0][ks], bl, acc0[c], 0, 0, 0);
            acc0[c] = __builtin_amdgcn_mfma_f32_16x16x32_bf16(al[0][ks], bh, acc0[c], 0, 0, 0);
            acc1[c] = __builtin_amdgcn_mfma_f32_16x16x32_bf16(ah[1][ks], bh, acc1[c], 0, 0, 0);
            acc1[c] = __builtin_amdgcn_mfma_f32_16x16x32_bf16(ah[1][ks], bl, acc1[c], 0, 0, 0);
            acc1[c] = __builtin_amdgcn_mfma_f32_16x16x32_bf16(al[1][ks], bh, acc1[c], 0, 0, 0);
        }
    }

    // ---- epilogue v2: stage through LDS, write full lines ----
    __syncthreads();                      // all W reads done; LDS reusable
    float* Ylds = (float*)Wlds;           // 128 x YSTR floats = 66048 B

#pragma unroll
    for (int mt = 0; mt < 2; mt++) {
        int rowloc = wave * 32 + mt * 16 + oct * 4;
#pragma unroll
        for (int c = 0; c < 8; c++) {
            int col = c * 16 + m16;
            float b = bias[col];
            floatx4 a = mt == 0 ? acc0[c] : acc1[c];
#pragma unroll
            for (int r = 0; r < 4; r++) {
                Ylds[(rowloc + r) * YSTR + col] = fmaxf(a[r] + b, 0.f);
            }
        }
    }
    __syncthreads();

    int gbase = blockIdx.x * 128;
    for (int i = t; i < 128 * 64; i += 256) {   // 64 float2 per row
        int row = i >> 6;
        int c2  = i & 63;
        int grow = gbase + row;
        if (grow < n) {
            float2 v;
            v.x = Ylds[row * YSTR + c2 * 2];
            v.y = Ylds[row * YSTR + c2 * 2 + 1];
            ((float2*)(out + (size_t)grow * HID))[c2] = v;
        }
    }
}

// ---------- launch ----------

extern "C" void kernel_launch(void* const* d_in, const int* in_sizes, int n_in,
                              void* d_out, int out_size, void* d_ws, size_t ws_size,
                              hipStream_t stream) {
    const int* ei = (const int*)d_in[0];          // (2, E) int32
    const float* emb = (const float*)d_in[1];     // (N, 128)
    const float* Ws = (const float*)d_in[2];      // (3, 128, 128)
    const float* bs = (const float*)d_in[3];      // (3, 128)

    const int E = in_sizes[0] / 2;                // 600000
    const int N = in_sizes[1] / HID;              // 100000
    const int NL = in_sizes[3] / HID;             // 3
    const int TOT = E + N;
    const int NPAD = ((N + 127) / 128) * 128;     // 100096 (A-loads unmasked)

    // workspace carve-up (256B aligned)
    char* p = (char*)d_ws;
    auto carve = [&](size_t bytes) {
        char* r = p;
        p += (bytes + 255) & ~(size_t)255;
        return (void*)r;
    };
    int*    cnt      = (int*)   carve((size_t)N * 4);
    int*    offsets  = (int*)   carve((size_t)(N + 1) * 4);
    int*    cursor   = (int*)   carve((size_t)N * 4);
    float*  dinv     = (float*) carve((size_t)N * 4);
    int*    csum     = (int*)   carve(1024 * 4);
    int2*   adj      = (int2*)  carve((size_t)TOT * 8);
    ushort* yh       = (ushort*)carve((size_t)NPAD * HID * 2);
    ushort* yl       = (ushort*)carve((size_t)NPAD * HID * 2);
    ushort* Whp      = (ushort*)carve((size_t)NL * HID * HID * 2);
    ushort* Wlp      = (ushort*)carve((size_t)NL * HID * HID * 2);
    float*  xbufA    = (float*) carve((size_t)N * HID * 4);
    float*  xbufB    = (float*) d_out;    // l0 and l2 outputs land here

    const int NCHUNK = (N + 1023) / 1024;   // 98 <= 256 (scan capacity)
    const int packBlocks = (NL * HID * HID + 255) / 256;        // 192
    const int edgeBlocks = ((E >> 2) + 255) / 256;              // 586
    const int cpBlocks = packBlocks + (edgeBlocks > 0 ? edgeBlocks : 1);

    (void)hipMemsetAsync(cnt, 0, (size_t)N * 4, stream);
    k_count_pack<<<cpBlocks, 256, 0, stream>>>(ei, cnt, E, Ws, Whp, Wlp, NL,
                                               packBlocks);
    k_scanA<<<NCHUNK, 256, 0, stream>>>(cnt, csum, N);
    k_scanC<<<NCHUNK, 256, 0, stream>>>(cnt, csum, offsets, cursor, dinv,
                                        adj, N, NCHUNK);
    k_fill_edges<<<(E + 255) / 256, 256, 0, stream>>>(ei, cursor, dinv, adj, E);

    // grid-stride agg: 2048 blocks (8 per CU, 32 waves/CU), ~12 nodes per wave
    const int aggBlocks = 2048;
    const int gemmBlocks = NPAD / 128;    // 782
    // l0: emb -> d_out, l1: d_out -> xbufA, l2: xbufA -> d_out
    const float* x = emb;
    for (int l = 0; l < NL; l++) {
        float* o = (l == 1) ? xbufA : xbufB;
        k_agg<<<aggBlocks, 256, 0, stream>>>(x, offsets, adj, yh, yl, N);
        k_gemm_mfma<<<gemmBlocks, 256, 0, stream>>>(yh, yl,
                                                    Whp + (size_t)l * HID * HID,
                                                    Wlp + (size_t)l * HID * HID,
                                                    bs + (size_t)l * HID, o, N);
        x = o;
    }
}